// Round 6
// baseline (220.368 us; speedup 1.0000x reference)
//
#include <hip/hip_runtime.h>
#include <hip/hip_bf16.h>
#include <stdint.h>

// Problem constants
#define Bn 16
#define Ln 4096
#define KF 384   // IN_F
#define OF 384   // OUT_F

// GEMM tiling
#define BM 128
#define BN 128
#define BK 64
#define LDX 72   // padded leading dim (elements) for transposed X tile

static constexpr float kScale = 0.051031036307982884f;  // 1/sqrt(384)

typedef __attribute__((ext_vector_type(4))) float f32x4;
typedef __attribute__((ext_vector_type(2))) float f32x2;
typedef __attribute__((ext_vector_type(8))) short short8;   // 8 bf16 (4 VGPR) MFMA A/B frag
typedef __attribute__((ext_vector_type(4))) float floatx4;  // MFMA C/D frag
typedef __attribute__((ext_vector_type(4))) unsigned int uint4v;

// float -> bf16 bits, round-to-nearest-even (finite inputs only)
__device__ __forceinline__ unsigned int f2bf_bits(float f) {
  union { float f; unsigned int u; } v;
  v.f = f;
  return (v.u + 0x7FFFu + ((v.u >> 16) & 1u)) >> 16;
}
__device__ __forceinline__ unsigned int pack2bf(float lo, float hi) {
  return f2bf_bits(lo) | (f2bf_bits(hi) << 16);
}

// HW packed f32->bf16 (RNE, bit-identical to pack2bf; validated round 3)
__device__ __forceinline__ unsigned int cvt_pk_bf16(float lo, float hi) {
  unsigned int r;
  asm("v_cvt_pk_bf16_f32 %0, %1, %2" : "=v"(r) : "v"(lo), "v"(hi));
  return r;
}

// Kernel 1: wmod[b][o][k] = bf16( SCALE*weight[o][k]*y[b][k] * rsqrt(sum_k(.)^2 + eps) )
__global__ __launch_bounds__(256) void modw_kernel(const float* __restrict__ weight,
                                                   const float* __restrict__ y,
                                                   unsigned short* __restrict__ wmod) {
  int t = threadIdx.x;
  int wv = t >> 6, lane = t & 63;
  int row = blockIdx.x * 4 + wv;  // [0, Bn*OF)
  int b = row / OF, o = row % OF;
  const float* wr = weight + o * KF;
  const float* yr = y + b * KF;
  float vals[6];
  float ss = 0.f;
#pragma unroll
  for (int j = 0; j < 3; ++j) {
    int k = (lane + 64 * j) * 2;
    f32x2 wvv = *(const f32x2*)(wr + k);
    f32x2 yv = *(const f32x2*)(yr + k);
    float t0 = kScale * wvv[0] * yv[0];
    float t1 = kScale * wvv[1] * yv[1];
    vals[2 * j] = t0;
    vals[2 * j + 1] = t1;
    ss += t0 * t0 + t1 * t1;
  }
#pragma unroll
  for (int off = 32; off >= 1; off >>= 1) ss += __shfl_xor(ss, off, 64);
  float d = rsqrtf(ss + 1e-8f);
  unsigned short* orow = wmod + row * KF;
#pragma unroll
  for (int j = 0; j < 3; ++j) {
    int k = (lane + 64 * j) * 2;
    *(unsigned int*)(orow + k) = pack2bf(vals[2 * j] * d, vals[2 * j + 1] * d);
  }
}

// Kernel 2: per batch b: out[o][p] = sum_k wmod[b][o][k] * X[b][k][p]
// NO-sA variant: A fragments load DIRECTLY from global (wmod is 4.7MB,
// L2/L3-hot). The r0 swizzle algebra cancels (asw = lane&7 = arow&7), so the
// global k-mapping is plainly k = kc*64 + ((s<<2)|quad)*8 at row arow+mi*16 —
// one 16B dwordx4 per fragment, wave = 16 rows x 64B segments. LDS holds only
// sX (double-buffered, 36KB -> 3 blocks/CU at the (256,3) register budget).
// ONE barrier per chunk, gating only sX publication (no DMA coupling):
//   chunk c: [load af | ds_read bf | MFMA]x2 ; cvt xv->sX[^1]; barrier; load X(c+2)
// X loads issued post-barrier, consumed pre-next-barrier -> no useful
// in-flight VMEM is ever drained by a barrier.
__global__ __launch_bounds__(256, 3) void gemm_kernel(const float* __restrict__ X,
                                                      const unsigned short* __restrict__ Wm,
                                                      float* __restrict__ out) {
  __shared__ unsigned short sX[2][BN * LDX];  // [p][k-chunk swizzled], 18KB each

  // XCD swizzle: 3 consecutive logical blocks (sharing an X tile) -> same XCD
  int flat = blockIdx.x;                         // 0..1535
  int logical = (flat & 7) * 192 + (flat >> 3);  // bijection
  int mt = logical % 3;
  int nt = (logical / 3) & 31;
  int b = logical / 96;

  int t = threadIdx.x;
  int wave = t >> 6, lane = t & 63;
  int quad = lane >> 4;

  const float* Xb = X + b * (KF * Ln);
  const unsigned short* Wb = Wm + (b * OF + mt * BM) * KF;
  int pbase = nt * BN;

  floatx4 acc[4][4] = {};

  int i31 = t & 31;
  int p0 = i31 * 4;          // X staging: this thread's 4 columns
  int kr0 = (t >> 5) * 8;    // and 8 k-rows (natural)
  int kr0s = (((t >> 5) ^ (i31 & 7)) * 8);  // swizzled LDS k-offset for writes
  int arow = (wave >> 1) * 64 + (lane & 15);
  int brow = (wave & 1) * 64 + (lane & 15);
  int xsw = ((lane & 15) >> 2);             // sX read swizzle base (m4)

  // Per-lane A pointer: row arow, k base quad*8 (global k-mapping, swizzle-free)
  const unsigned short* Wl = Wb + arow * KF + quad * 8;

  f32x4 xv[8];
  unsigned int wv4[4][4];

  // ---- prologue: load+convert+write X(0); barrier; issue X(1) ----
  {
    const float* xsrc = Xb + (0 + kr0) * Ln + pbase + p0;
#pragma unroll
    for (int i = 0; i < 8; ++i) xv[i] = *(const f32x4*)(xsrc + i * Ln);
#pragma unroll
    for (int j = 0; j < 4; ++j)
#pragma unroll
      for (int i = 0; i < 4; ++i)
        wv4[j][i] = cvt_pk_bf16(xv[2 * i][j], xv[2 * i + 1][j]);
#pragma unroll
    for (int j = 0; j < 4; ++j)
      *(uint4v*)(&sX[0][(p0 + j) * LDX + kr0s]) = *(uint4v*)wv4[j];
  }
  __syncthreads();  // publishes sX(0)
  {
    const float* xsrc = Xb + (BK + kr0) * Ln + pbase + p0;
#pragma unroll
    for (int i = 0; i < 8; ++i) xv[i] = *(const f32x4*)(xsrc + i * Ln);
  }

#pragma unroll
  for (int kc = 0; kc < 6; ++kc) {
    int cur = kc & 1;
    // ---- MFMA on current chunk; A frags direct from global (L2-hot) ----
#pragma unroll
    for (int s = 0; s < 2; ++s) {
      short8 af[4], bf[4];
#pragma unroll
      for (int mi = 0; mi < 4; ++mi)
        af[mi] = *(const short8*)(Wl + mi * 16 * KF + kc * BK + s * 32);
#pragma unroll
      for (int ni = 0; ni < 4; ++ni) {
        int cx = (((s << 2) | quad) ^ (((ni & 1) << 2) | xsw)) * 8;
        bf[ni] = *(const short8*)(&sX[cur][(brow + ni * 16) * LDX + cx]);
      }
      __builtin_amdgcn_s_setprio(1);
#pragma unroll
      for (int mi = 0; mi < 4; ++mi)
#pragma unroll
        for (int ni = 0; ni < 4; ++ni)
          acc[mi][ni] = __builtin_amdgcn_mfma_f32_16x16x32_bf16(af[mi], bf[ni], acc[mi][ni], 0, 0, 0);
      __builtin_amdgcn_s_setprio(0);
    }
    // ---- convert X(kc+1) (loaded last iter), publish to other sX buffer ----
    if (kc < 5) {
#pragma unroll
      for (int j = 0; j < 4; ++j)
#pragma unroll
        for (int i = 0; i < 4; ++i)
          wv4[j][i] = cvt_pk_bf16(xv[2 * i][j], xv[2 * i + 1][j]);
#pragma unroll
      for (int j = 0; j < 4; ++j)
        *(uint4v*)(&sX[cur ^ 1][(p0 + j) * LDX + kr0s]) = *(uint4v*)wv4[j];
      __syncthreads();  // publishes sX(kc+1); nothing useful in-flight to drain
      // ---- issue X loads for chunk kc+2 (consumed one full chunk later) ----
      if (kc < 4) {
        const float* xsrc = Xb + ((kc + 2) * BK + kr0) * Ln + pbase + p0;
#pragma unroll
        for (int i = 0; i < 8; ++i) xv[i] = *(const f32x4*)(xsrc + i * Ln);
      }
    }
  }

  // --- epilogue: C/D layout col=lane&15, row=quad*4+r (verbatim, proven) ---
  float* outb = out + (b * OF + mt * BM) * Ln + pbase;
  int col = lane & 15;
#pragma unroll
  for (int mi = 0; mi < 4; ++mi) {
    int ob = (wave >> 1) * 64 + mi * 16 + quad * 4;
#pragma unroll
    for (int ni = 0; ni < 4; ++ni) {
      int p = (wave & 1) * 64 + ni * 16 + col;
#pragma unroll
      for (int r = 0; r < 4; ++r) outb[(ob + r) * Ln + p] = acc[mi][ni][r];
    }
  }
}

extern "C" void kernel_launch(void* const* d_in, const int* in_sizes, int n_in,
                              void* d_out, int out_size, void* d_ws, size_t ws_size,
                              hipStream_t stream) {
  const float* Efou = (const float*)d_in[0];    // [B, L, IN_F] fp32
  const float* y = (const float*)d_in[1];       // [B, IN_F] fp32
  const float* weight = (const float*)d_in[2];  // [1, OUT_F, IN_F] fp32
  float* out = (float*)d_out;                   // [B*OUT_F*L] fp32 (flat)
  unsigned short* wmod = (unsigned short*)d_ws; // [B, OUT_F, IN_F] bf16, 4.7MB

  modw_kernel<<<(Bn * OF) / 4, 256, 0, stream>>>(weight, y, wmod);
  gemm_kernel<<<Bn * (OF / BM) * (Ln / BN), 256, 0, stream>>>(Efou, wmod, out);
}

// Round 7
// 198.740 us; speedup vs baseline: 1.1088x; 1.1088x over previous
//
#include <hip/hip_runtime.h>
#include <hip/hip_bf16.h>
#include <stdint.h>

// Problem constants
#define Bn 16
#define Ln 4096
#define KF 384   // IN_F
#define OF 384   // OUT_F

// GEMM tiling
#define BM 128
#define BN 128
#define BK 64
#define LDX 72   // padded leading dim (elements) for transposed X tile

static constexpr float kScale = 0.051031036307982884f;  // 1/sqrt(384)

typedef __attribute__((ext_vector_type(4))) float f32x4;
typedef __attribute__((ext_vector_type(2))) float f32x2;
typedef __attribute__((ext_vector_type(8))) short short8;   // 8 bf16 (4 VGPR) MFMA A/B frag
typedef __attribute__((ext_vector_type(4))) float floatx4;  // MFMA C/D frag
typedef __attribute__((ext_vector_type(4))) unsigned int uint4v;

__device__ __forceinline__ void gl_lds16(const void* g, void* l) {
  __builtin_amdgcn_global_load_lds(
      (const __attribute__((address_space(1))) unsigned int*)g,
      (__attribute__((address_space(3))) unsigned int*)l, 16, 0, 0);
}

// float -> bf16 bits, round-to-nearest-even (finite inputs only)
__device__ __forceinline__ unsigned int f2bf_bits(float f) {
  union { float f; unsigned int u; } v;
  v.f = f;
  return (v.u + 0x7FFFu + ((v.u >> 16) & 1u)) >> 16;
}
__device__ __forceinline__ unsigned int pack2bf(float lo, float hi) {
  return f2bf_bits(lo) | (f2bf_bits(hi) << 16);
}

// HW packed f32->bf16 (RNE, bit-identical to pack2bf; validated round 3)
__device__ __forceinline__ unsigned int cvt_pk_bf16(float lo, float hi) {
  unsigned int r;
  asm("v_cvt_pk_bf16_f32 %0, %1, %2" : "=v"(r) : "v"(lo), "v"(hi));
  return r;
}

// Kernel 1: wmod[b][o][k] = bf16( SCALE*weight[o][k]*y[b][k] * rsqrt(sum_k(.)^2 + eps) )
__global__ __launch_bounds__(256) void modw_kernel(const float* __restrict__ weight,
                                                   const float* __restrict__ y,
                                                   unsigned short* __restrict__ wmod) {
  int t = threadIdx.x;
  int wv = t >> 6, lane = t & 63;
  int row = blockIdx.x * 4 + wv;  // [0, Bn*OF)
  int b = row / OF, o = row % OF;
  const float* wr = weight + o * KF;
  const float* yr = y + b * KF;
  float vals[6];
  float ss = 0.f;
#pragma unroll
  for (int j = 0; j < 3; ++j) {
    int k = (lane + 64 * j) * 2;
    f32x2 wvv = *(const f32x2*)(wr + k);
    f32x2 yv = *(const f32x2*)(yr + k);
    float t0 = kScale * wvv[0] * yv[0];
    float t1 = kScale * wvv[1] * yv[1];
    vals[2 * j] = t0;
    vals[2 * j + 1] = t1;
    ss += t0 * t0 + t1 * t1;
  }
#pragma unroll
  for (int off = 32; off >= 1; off >>= 1) ss += __shfl_xor(ss, off, 64);
  float d = rsqrtf(ss + 1e-8f);
  unsigned short* orow = wmod + row * KF;
#pragma unroll
  for (int j = 0; j < 3; ++j) {
    int k = (lane + 64 * j) * 2;
    *(unsigned int*)(orow + k) = pack2bf(vals[2 * j] * d, vals[2 * j + 1] * d);
  }
}

// Kernel 2: per batch b: out[o][p] = sum_k wmod[b][o][k] * X[b][k][p]
// r4 skeleton (both tiles dbuf, one sync/chunk, proven data paths verbatim)
// with __syncthreads REPLACED by counted-vmcnt + raw s_barrier (T4): the
// X(kc+2) prefetch stays IN FLIGHT across the barrier instead of being
// drained by syncthreads' implicit s_waitcnt vmcnt(0).
// Per chunk, issue order fixes the vmcnt arithmetic:
//   a) A-DMA(kc+1) [4 vmem, oldest]
//   b) MFMA(kc) from sA/sX[cur]
//   c) convert xv=X(kc+1)   (compiler auto-waits vmcnt(4): X older than DMA)
//   d) ds_write sX[^1]
//   e) issue X(kc+2) [8 vmem, newest]
//   f) s_waitcnt vmcnt(8)   -> retires the 4 A-DMAs, X(kc+2) keeps flying
//      s_waitcnt lgkmcnt(0) -> own ds_writes visible
//      s_barrier            -> publishes sA/sX[^1]; nothing useful drained
__global__ __launch_bounds__(256, 3) void gemm_kernel(const float* __restrict__ X,
                                                      const unsigned short* __restrict__ Wm,
                                                      float* __restrict__ out) {
  __shared__ unsigned short sA[2][BM * BK];  // [o][k-chunk swizzled by o&7], 16KB each
  __shared__ unsigned short sX[2][BN * LDX]; // [p][k-chunk swizzled], 18KB each

  // XCD swizzle: 3 consecutive logical blocks (sharing an X tile) -> same XCD
  int flat = blockIdx.x;                         // 0..1535
  int logical = (flat & 7) * 192 + (flat >> 3);  // bijection
  int mt = logical % 3;
  int nt = (logical / 3) & 31;
  int b = logical / 96;

  int t = threadIdx.x;
  int wave = t >> 6, lane = t & 63;
  int quad = lane >> 4;

  const float* Xb = X + b * (KF * Ln);
  const unsigned short* Wb = Wm + (b * OF + mt * BM) * KF;
  int pbase = nt * BN;

  floatx4 acc[4][4] = {};

  int i31 = t & 31;
  int p0 = i31 * 4;          // X staging: this thread's 4 columns
  int kr0 = (t >> 5) * 8;    // and 8 k-rows (natural)
  int kr0s = (((t >> 5) ^ (i31 & 7)) * 8);  // swizzled LDS k-offset for writes
  int arow = (wave >> 1) * 64 + (lane & 15);
  int brow = (wave & 1) * 64 + (lane & 15);
  int asw = lane & 7;                       // sA read swizzle
  int xsw = ((lane & 15) >> 2);             // sX read swizzle base (m4)

  // A staging geometry (verbatim): LDS dest base + lane*16; source k-chunk is
  // XOR-permuted so that LDS chunk c' holds global chunk c'^(row&7).
  int aoff[4], asrc_row[4], asrc_c[4];
#pragma unroll
  for (int j = 0; j < 4; ++j) {
    int boff = wave * 4096 + j * 1024 + lane * 16;  // byte offset in 16KB tile
    int row = boff >> 7;                            // 128B per row (64 bf16)
    int cp = (boff >> 4) & 7;                       // LDS chunk slot
    aoff[j] = boff;
    asrc_row[j] = row;
    asrc_c[j] = (cp ^ (row & 7)) * 8;               // global k-element offset
  }

  f32x4 xv[8];
  unsigned int wv4[4][4];

  // ---- prologue: DMA A(0); load+convert+write X(0); issue X(1); barrier ----
#pragma unroll
  for (int j = 0; j < 4; ++j)
    gl_lds16(Wb + asrc_row[j] * KF + 0 + asrc_c[j], (char*)sA[0] + aoff[j]);
  {
    const float* xsrc = Xb + (0 + kr0) * Ln + pbase + p0;
#pragma unroll
    for (int i = 0; i < 8; ++i) xv[i] = *(const f32x4*)(xsrc + i * Ln);
#pragma unroll
    for (int j = 0; j < 4; ++j)
#pragma unroll
      for (int i = 0; i < 4; ++i)
        wv4[j][i] = cvt_pk_bf16(xv[2 * i][j], xv[2 * i + 1][j]);  // auto-waits X(0)+A(0)
#pragma unroll
    for (int j = 0; j < 4; ++j)
      *(uint4v*)(&sX[0][(p0 + j) * LDX + kr0s]) = *(uint4v*)wv4[j];
  }
  {
    const float* xsrc = Xb + (BK + kr0) * Ln + pbase + p0;  // X(1)
#pragma unroll
    for (int i = 0; i < 8; ++i) xv[i] = *(const f32x4*)(xsrc + i * Ln);
  }
  asm volatile("s_waitcnt lgkmcnt(0)" ::: "memory");
  __builtin_amdgcn_sched_barrier(0);
  __builtin_amdgcn_s_barrier();  // publishes sA(0)+sX(0); X(1) stays in flight

#pragma unroll
  for (int kc = 0; kc < 6; ++kc) {
    int cur = kc & 1;
    // ---- (a) issue A DMA for next chunk into the other buffer ----
    if (kc < 5) {
      int k0n = (kc + 1) * BK;
#pragma unroll
      for (int j = 0; j < 4; ++j)
        gl_lds16(Wb + asrc_row[j] * KF + k0n + asrc_c[j], (char*)sA[cur ^ 1] + aoff[j]);
    }
    // ---- (b) MFMA on current chunk ----
#pragma unroll
    for (int s = 0; s < 2; ++s) {
      short8 af[4], bf[4];
#pragma unroll
      for (int mi = 0; mi < 4; ++mi) {
        int ca = (((s << 2) | quad) ^ asw) * 8;
        af[mi] = *(const short8*)(&sA[cur][(arow + mi * 16) * BK + ca]);
      }
#pragma unroll
      for (int ni = 0; ni < 4; ++ni) {
        int cx = (((s << 2) | quad) ^ (((ni & 1) << 2) | xsw)) * 8;
        bf[ni] = *(const short8*)(&sX[cur][(brow + ni * 16) * LDX + cx]);
      }
      __builtin_amdgcn_s_setprio(1);
#pragma unroll
      for (int mi = 0; mi < 4; ++mi)
#pragma unroll
        for (int ni = 0; ni < 4; ++ni)
          acc[mi][ni] = __builtin_amdgcn_mfma_f32_16x16x32_bf16(af[mi], bf[ni], acc[mi][ni], 0, 0, 0);
      __builtin_amdgcn_s_setprio(0);
    }
    if (kc < 5) {
      // ---- (c) convert xv = X(kc+1); compiler auto-waits only the X loads ----
#pragma unroll
      for (int j = 0; j < 4; ++j)
#pragma unroll
        for (int i = 0; i < 4; ++i)
          wv4[j][i] = cvt_pk_bf16(xv[2 * i][j], xv[2 * i + 1][j]);
      // ---- (d) publish-pending write to the other sX buffer ----
#pragma unroll
      for (int j = 0; j < 4; ++j)
        *(uint4v*)(&sX[cur ^ 1][(p0 + j) * LDX + kr0s]) = *(uint4v*)wv4[j];
      // ---- (e) issue X loads for chunk kc+2 (stay in flight across barrier) ----
      if (kc < 4) {
        const float* xsrc = Xb + ((kc + 2) * BK + kr0) * Ln + pbase + p0;
#pragma unroll
        for (int i = 0; i < 8; ++i) xv[i] = *(const f32x4*)(xsrc + i * Ln);
      }
      // ---- (f) counted waits + raw barrier ----
      if (kc < 4) {
        asm volatile("s_waitcnt vmcnt(8)" ::: "memory");   // retire 4 A-DMAs (oldest)
      } else {
        asm volatile("s_waitcnt vmcnt(0)" ::: "memory");   // tail: nothing else in flight
      }
      asm volatile("s_waitcnt lgkmcnt(0)" ::: "memory");   // own ds_writes done
      __builtin_amdgcn_sched_barrier(0);
      __builtin_amdgcn_s_barrier();  // publishes sA(kc+1)+sX(kc+1)
    }
  }

  // --- epilogue: C/D layout col=lane&15, row=quad*4+r (verbatim, proven) ---
  float* outb = out + (b * OF + mt * BM) * Ln + pbase;
  int col = lane & 15;
#pragma unroll
  for (int mi = 0; mi < 4; ++mi) {
    int ob = (wave >> 1) * 64 + mi * 16 + quad * 4;
#pragma unroll
    for (int ni = 0; ni < 4; ++ni) {
      int p = (wave & 1) * 64 + ni * 16 + col;
#pragma unroll
      for (int r = 0; r < 4; ++r) outb[(ob + r) * Ln + p] = acc[mi][ni][r];
    }
  }
}

extern "C" void kernel_launch(void* const* d_in, const int* in_sizes, int n_in,
                              void* d_out, int out_size, void* d_ws, size_t ws_size,
                              hipStream_t stream) {
  const float* Efou = (const float*)d_in[0];    // [B, L, IN_F] fp32
  const float* y = (const float*)d_in[1];       // [B, IN_F] fp32
  const float* weight = (const float*)d_in[2];  // [1, OUT_F, IN_F] fp32
  float* out = (float*)d_out;                   // [B*OUT_F*L] fp32 (flat)
  unsigned short* wmod = (unsigned short*)d_ws; // [B, OUT_F, IN_F] bf16, 4.7MB

  modw_kernel<<<(Bn * OF) / 4, 256, 0, stream>>>(weight, y, wmod);
  gemm_kernel<<<Bn * (OF / BM) * (Ln / BN), 256, 0, stream>>>(Efou, wmod, out);
}